// Round 1
// baseline (144.656 us; speedup 1.0000x reference)
//
#include <hip/hip_runtime.h>
#include <math.h>

#define RADIUS 10
#define WIN    21            // 2*RADIUS+1
#define GWIN   23            // WIN + 2 (halo for 3x3 sobel)
#define Hdim   512
#define Wdim   512
#define Bdim   32
#define Ndim   68
#define Cdim   3

// scale = PENALTY_WEIGHT / (B*N + 1e-8)
__device__ __constant__ float kScale = (float)(1.0 / (2176.0 + 1e-8));

__global__ __launch_bounds__(256) void gp_loss_kernel(
    const float* __restrict__ lm,   // (B,N,2)
    const float* __restrict__ img,  // (B,3,H,W)
    const float* __restrict__ vis,  // (B,N)
    float* __restrict__ out)        // scalar
{
    const int bn = blockIdx.x;                 // 0 .. B*N-1
    const int b  = bn / Ndim;

    if (vis[bn] < 0.5f) return;                // invisible -> contributes 0

    const float lx = lm[2 * bn + 0];
    const float ly = lm[2 * bn + 1];
    int px = (int)truncf(lx * (float)Wdim);  px = min(max(px, 0), Wdim - 1);
    int py = (int)truncf(ly * (float)Hdim);  py = min(max(py, 0), Hdim - 1);

    __shared__ float g[GWIN][GWIN + 1];        // +1 pad: conflict-free rows
    __shared__ float wsum[4];

    const int tid = threadIdx.x;
    const float* img0 = img + (size_t)b * Cdim * Hdim * Wdim;

    // ---- stage 23x23 gray window into LDS (0 outside image = conv zero-pad) ----
    for (int i = tid; i < GWIN * GWIN; i += 256) {
        const int ry = i / GWIN, rx = i % GWIN;
        const int y = py - RADIUS - 1 + ry;
        const int x = px - RADIUS - 1 + rx;
        float v = 0.0f;
        if (y >= 0 && y < Hdim && x >= 0 && x < Wdim) {
            const size_t idx = (size_t)y * Wdim + x;
            v = 0.299f * img0[idx]
              + 0.587f * img0[idx + (size_t)Hdim * Wdim]
              + 0.114f * img0[idx + (size_t)2 * Hdim * Wdim];
        }
        g[ry][rx] = v;
    }
    __syncthreads();

    // ---- sobel magnitude over the 21x21 window, masked to valid pixels ----
    float sum = 0.0f;
    for (int i = tid; i < WIN * WIN; i += 256) {
        const int dy = i / WIN, dx = i % WIN;
        const int y = py - RADIUS + dy;
        const int x = px - RADIUS + dx;
        if (y >= 0 && y < Hdim && x >= 0 && x < Wdim) {
            const int cy = dy + 1, cx = dx + 1;
            const float a00 = g[cy - 1][cx - 1], a01 = g[cy - 1][cx], a02 = g[cy - 1][cx + 1];
            const float a10 = g[cy    ][cx - 1],                      a12 = g[cy    ][cx + 1];
            const float a20 = g[cy + 1][cx - 1], a21 = g[cy + 1][cx], a22 = g[cy + 1][cx + 1];
            const float gx = (a02 - a00) + 2.0f * (a12 - a10) + (a22 - a20);
            const float gy = (a20 - a00) + 2.0f * (a21 - a01) + (a22 - a02);
            sum += sqrtf(gx * gx + gy * gy);
        }
    }

    // ---- block reduction: wave64 shuffle, then across the 4 waves ----
    #pragma unroll
    for (int o = 32; o > 0; o >>= 1) sum += __shfl_down(sum, o, 64);
    if ((tid & 63) == 0) wsum[tid >> 6] = sum;
    __syncthreads();

    if (tid == 0) {
        const float s = wsum[0] + wsum[1] + wsum[2] + wsum[3];
        // analytic mask count: (#valid rows) * (#valid cols)
        const int cnty = min(py + RADIUS, Hdim - 1) - max(py - RADIUS, 0) + 1;
        const int cntx = min(px + RADIUS, Wdim - 1) - max(px - RADIUS, 0) + 1;
        const float contrib = (s / (float)(cnty * cntx)) * kScale;
        atomicAdd(out, contrib);
    }
}

extern "C" void kernel_launch(void* const* d_in, const int* in_sizes, int n_in,
                              void* d_out, int out_size, void* d_ws, size_t ws_size,
                              hipStream_t stream) {
    const float* lm  = (const float*)d_in[0];   // (32,68,2)
    const float* img = (const float*)d_in[1];   // (32,3,512,512)
    const float* vis = (const float*)d_in[2];   // (32,68)
    float* out = (float*)d_out;

    hipMemsetAsync(out, 0, sizeof(float), stream);
    gp_loss_kernel<<<Bdim * Ndim, 256, 0, stream>>>(lm, img, vis, out);
}

// Round 2
// 135.752 us; speedup vs baseline: 1.0656x; 1.0656x over previous
//
#include <hip/hip_runtime.h>
#include <math.h>

#define RADIUS 10
#define WIN    21            // 2*RADIUS+1
#define GWIN   23            // WIN + 2 (halo for 3x3 sobel)
#define Hdim   512
#define Wdim   512
#define Bdim   32
#define Ndim   68
#define Cdim   3
#define NBN    (Bdim * Ndim) // 2176 landmarks

// Stage 1: one block per landmark -> partial[bn] = local_mean (0 if invisible)
__global__ __launch_bounds__(256) void gp_win_kernel(
    const float* __restrict__ lm,      // (B,N,2)
    const float* __restrict__ img,     // (B,3,H,W)
    const float* __restrict__ vis,     // (B,N)
    float* __restrict__ partial)       // (B*N,)
{
    const int bn  = blockIdx.x;
    const int b   = bn / Ndim;
    const int tid = threadIdx.x;

    if (vis[bn] < 0.5f) {              // invisible -> contributes 0
        if (tid == 0) partial[bn] = 0.0f;
        return;
    }

    const float lx = lm[2 * bn + 0];
    const float ly = lm[2 * bn + 1];
    int px = (int)truncf(lx * (float)Wdim);  px = min(max(px, 0), Wdim - 1);
    int py = (int)truncf(ly * (float)Hdim);  py = min(max(py, 0), Hdim - 1);

    __shared__ float g[GWIN][GWIN + 1];  // +1 pad: conflict-free rows
    __shared__ float wsum[4];

    const float* img0 = img + (size_t)b * Cdim * Hdim * Wdim;

    // ---- stage 23x23 gray window into LDS (0 outside image = conv zero-pad) ----
    for (int i = tid; i < GWIN * GWIN; i += 256) {
        const int ry = i / GWIN, rx = i % GWIN;
        const int y = py - RADIUS - 1 + ry;
        const int x = px - RADIUS - 1 + rx;
        float v = 0.0f;
        if (y >= 0 && y < Hdim && x >= 0 && x < Wdim) {
            const size_t idx = (size_t)y * Wdim + x;
            v = 0.299f * img0[idx]
              + 0.587f * img0[idx + (size_t)Hdim * Wdim]
              + 0.114f * img0[idx + (size_t)2 * Hdim * Wdim];
        }
        g[ry][rx] = v;
    }
    __syncthreads();

    // ---- sobel magnitude over the 21x21 window, masked to valid pixels ----
    float sum = 0.0f;
    for (int i = tid; i < WIN * WIN; i += 256) {
        const int dy = i / WIN, dx = i % WIN;
        const int y = py - RADIUS + dy;
        const int x = px - RADIUS + dx;
        if (y >= 0 && y < Hdim && x >= 0 && x < Wdim) {
            const int cy = dy + 1, cx = dx + 1;
            const float a00 = g[cy - 1][cx - 1], a01 = g[cy - 1][cx], a02 = g[cy - 1][cx + 1];
            const float a10 = g[cy    ][cx - 1],                      a12 = g[cy    ][cx + 1];
            const float a20 = g[cy + 1][cx - 1], a21 = g[cy + 1][cx], a22 = g[cy + 1][cx + 1];
            const float gx = (a02 - a00) + 2.0f * (a12 - a10) + (a22 - a20);
            const float gy = (a20 - a00) + 2.0f * (a21 - a01) + (a22 - a02);
            sum += sqrtf(gx * gx + gy * gy);
        }
    }

    // ---- block reduction: wave64 shuffle, then across the 4 waves ----
    #pragma unroll
    for (int o = 32; o > 0; o >>= 1) sum += __shfl_down(sum, o, 64);
    if ((tid & 63) == 0) wsum[tid >> 6] = sum;
    __syncthreads();

    if (tid == 0) {
        const float s = wsum[0] + wsum[1] + wsum[2] + wsum[3];
        // analytic mask count: (#valid rows) * (#valid cols)
        const int cnty = min(py + RADIUS, Hdim - 1) - max(py - RADIUS, 0) + 1;
        const int cntx = min(px + RADIUS, Wdim - 1) - max(px - RADIUS, 0) + 1;
        partial[bn] = s / (float)(cnty * cntx);
    }
}

// Stage 2: single block reduces the 2176 partials, writes the scalar output.
__global__ __launch_bounds__(256) void gp_reduce_kernel(
    const float* __restrict__ partial, float* __restrict__ out)
{
    const int tid = threadIdx.x;
    float sum = 0.0f;
    for (int i = tid; i < NBN; i += 256) sum += partial[i];
    #pragma unroll
    for (int o = 32; o > 0; o >>= 1) sum += __shfl_down(sum, o, 64);
    __shared__ float wsum[4];
    if ((tid & 63) == 0) wsum[tid >> 6] = sum;
    __syncthreads();
    if (tid == 0) {
        const float kScale = (float)(1.0 / ((double)NBN + 1e-8)); // PENALTY_WEIGHT/(B*N+1e-8)
        out[0] = (wsum[0] + wsum[1] + wsum[2] + wsum[3]) * kScale;
    }
}

extern "C" void kernel_launch(void* const* d_in, const int* in_sizes, int n_in,
                              void* d_out, int out_size, void* d_ws, size_t ws_size,
                              hipStream_t stream) {
    const float* lm  = (const float*)d_in[0];   // (32,68,2)
    const float* img = (const float*)d_in[1];   // (32,3,512,512)
    const float* vis = (const float*)d_in[2];   // (32,68)
    float* partial = (float*)d_ws;              // 2176 floats of scratch
    float* out = (float*)d_out;

    gp_win_kernel<<<NBN, 256, 0, stream>>>(lm, img, vis, partial);
    gp_reduce_kernel<<<1, 256, 0, stream>>>(partial, out);
}